// Round 1
// baseline (491.246 us; speedup 1.0000x reference)
//
#include <hip/hip_runtime.h>
#include <hip/hip_bf16.h>

// EGAT MLP predictor: score[e, :] = concat(hn[src[e]], hn[dst[e]], he[e]) @ W^T + b
// E = 600000, D = 128 (3D = 384 = K), OUT = 16, all fp32 in/out.
//
// Strategy: memory-bound (he stream = 307 MB dominates; bf16-MFMA compute ~3 us
// vs ~60 us HBM floor). One wave per 16-edge tile using mfma_f32_16x16x32_bf16:
//   A operand: lane layout A[m=lane&15][k=quad*8+j] -> lane l holds edge
//              tile*16+l; each K-step's 8-float chunk is contiguous and lies in
//              exactly one of the 3 concat segments (steps 0-3: hn[src],
//              4-7: hn[dst], 8-11: he) -> segment choice is compile-time.
//   B operand: lane layout B[n=lane&15][k=quad*8+j] -> lane l holds W row l.
//              Both operands fed as [row][k] gives D = A*W^T (the gemm_bt form).
//   C/D:       col=lane&15 (out idx), row=quad*4+reg (edge in tile).
// W fragments (12 x short8 = 48 VGPRs) preloaded once per wave, amortized over
// 5 tiles/wave (1875 blocks * 4 waves * 5 = 37500 tiles, exact).

#define D      128
#define OUT    16
#define KTOT   384   // 3*D
#define KSTEPS 12    // KTOT / 32

typedef __attribute__((ext_vector_type(8))) short  short8;   // 8 bf16 (4 VGPRs)
typedef __attribute__((ext_vector_type(4))) float  float4v;  // 4 fp32

// fp32 -> bf16 with round-to-nearest-even (no NaN handling needed: inputs are
// finite Gaussians). 3-4 VALU ops/element.
__device__ __forceinline__ unsigned short f2bf(float x) {
    unsigned u = __builtin_bit_cast(unsigned, x);
    unsigned r = u + 0x7fffu + ((u >> 16) & 1u);
    return (unsigned short)(r >> 16);
}

// Load 8 contiguous fp32 (16B-aligned: offsets are multiples of 8 floats from
// 512B-aligned row bases) and convert to a bf16x8 MFMA fragment.
__device__ __forceinline__ short8 load_cvt8(const float* __restrict__ p) {
    float4v a = *(const float4v*)(p);
    float4v c = *(const float4v*)(p + 4);
    short8 r;
#pragma unroll
    for (int i = 0; i < 4; ++i) {
        r[i]     = (short)f2bf(a[i]);
        r[i + 4] = (short)f2bf(c[i]);
    }
    return r;
}

__global__ __launch_bounds__(256) void egat_mfma_kernel(
    const float* __restrict__ hn,   // [N_NODES, 128]
    const float* __restrict__ he,   // [E, 128]
    const int*   __restrict__ src,  // [E]
    const int*   __restrict__ dst,  // [E]
    const float* __restrict__ W,    // [16, 384]
    const float* __restrict__ b,    // [16]
    float*       __restrict__ out,  // [E, 16]
    int n_tiles, int total_waves)
{
    const int wave = (blockIdx.x * blockDim.x + threadIdx.x) >> 6;
    const int lane = threadIdx.x & 63;
    const int l    = lane & 15;   // A: edge-in-tile | B: W row / out col
    const int quad = lane >> 4;
    const int off  = quad * 8;    // k sub-offset within a 32-wide K step

    // Preload all 12 W fragments: wf[s] = bf16(W[l][s*32 + quad*8 .. +8]).
    // Hot in L1/L2 (every wave reads the same 24 KB).
    short8 wf[KSTEPS];
    const float* wrow = W + l * KTOT;
#pragma unroll
    for (int s = 0; s < KSTEPS; ++s)
        wf[s] = load_cvt8(wrow + s * 32 + off);

    const float bias = b[l];

    for (int tile = wave; tile < n_tiles; tile += total_waves) {
        const int e  = tile * 16 + l;          // this lane's edge (A operand)
        const int su = src[e];
        const int dv = dst[e];
        const float* ru = hn + (size_t)su * D;
        const float* rv = hn + (size_t)dv * D;
        const float* re = he + (size_t)e  * D;

        float4v acc = {0.f, 0.f, 0.f, 0.f};
        // K steps 0-3: hn[src] segment (global k = s*32 + quad*8)
#pragma unroll
        for (int s = 0; s < 4; ++s) {
            short8 af = load_cvt8(ru + s * 32 + off);
            acc = __builtin_amdgcn_mfma_f32_16x16x32_bf16(af, wf[s], acc, 0, 0, 0);
        }
        // K steps 4-7: hn[dst] segment
#pragma unroll
        for (int s = 0; s < 4; ++s) {
            short8 af = load_cvt8(rv + s * 32 + off);
            acc = __builtin_amdgcn_mfma_f32_16x16x32_bf16(af, wf[4 + s], acc, 0, 0, 0);
        }
        // K steps 8-11: he segment
#pragma unroll
        for (int s = 0; s < 4; ++s) {
            short8 af = load_cvt8(re + s * 32 + off);
            acc = __builtin_amdgcn_mfma_f32_16x16x32_bf16(af, wf[8 + s], acc, 0, 0, 0);
        }

        // D[row=edge-in-tile][col=out]: lane (quad,l) holds rows quad*4+i, col l.
        // Per (quad,i), the 16 lanes write 16 consecutive dwords (64B coalesced).
        const size_t ebase = (size_t)tile * 16;
#pragma unroll
        for (int i = 0; i < 4; ++i) {
            int row = quad * 4 + i;
            out[(ebase + row) * OUT + l] = acc[i] + bias;
        }
    }
}

extern "C" void kernel_launch(void* const* d_in, const int* in_sizes, int n_in,
                              void* d_out, int out_size, void* d_ws, size_t ws_size,
                              hipStream_t stream) {
    const float* hn  = (const float*)d_in[0];
    const float* he  = (const float*)d_in[1];
    const int*   src = (const int*)d_in[2];
    const int*   dst = (const int*)d_in[3];
    const float* W   = (const float*)d_in[4];
    const float* b   = (const float*)d_in[5];
    float* out = (float*)d_out;

    const int E = in_sizes[2];          // 600000 (divisible by 16)
    const int n_tiles = E / 16;         // 37500
    const int blocks = 1875;            // 4 waves/block * 5 tiles/wave exactly
    const int total_waves = blocks * 4;

    egat_mfma_kernel<<<blocks, 256, 0, stream>>>(hn, he, src, dst, W, b, out,
                                                 n_tiles, total_waves);
}

// Round 2
// 475.874 us; speedup vs baseline: 1.0323x; 1.0323x over previous
//
#include <hip/hip_runtime.h>
#include <hip/hip_bf16.h>

// EGAT MLP predictor: score[e,:] = concat(hn[src[e]], hn[dst[e]], he[e]) @ W^T + b
// E=600000, D=128 (K=384), OUT=16, fp32 in/out. bf16 MFMA 16x16x32, 1 wave/16-edge tile.
//
// R1 changes vs R0 (theory: latency-serialized at ~2 waves/SIMD):
//  - he tile staged global->LDS via global_load_lds dwordx4 (coalesced 1KB/instr,
//    per-wave private region, no barrier; s_waitcnt vmcnt(0) before ds_read).
//    LDS row stride 528B => ds_read_b128 bank-group uniform (conflict-free).
//  - W held in LDS as bf16 (stride 784B, conflict-free b128) => -48 VGPR/lane.
//  - src/dst prefetched one tile ahead => gather loads issue at tile top.
//  - 3 consecutive tiles/wave (he stream locality), 3125 blocks x 4 waves.

#define D      128
#define OUT    16
#define KTOT   384
// LDS geometry
#define HE_ROW_B   528                 // 512B data + 16B pad (16B-aligned stride)
#define HE_ROW_F   132                 // floats
#define HE_WAVE_F  2304                // 9216B per wave (9 x 1KB staging instrs)
#define W_ROW_S    392                 // ushorts per W row (784B stride)

typedef __attribute__((ext_vector_type(8))) short  short8;   // 8 bf16
typedef __attribute__((ext_vector_type(4))) float  float4v;

__device__ __forceinline__ unsigned short f2bf(float x) {
    unsigned u = __builtin_bit_cast(unsigned, x);
    unsigned r = u + 0x7fffu + ((u >> 16) & 1u);
    return (unsigned short)(r >> 16);
}

__device__ __forceinline__ short8 cvt8(float4v a, float4v c) {
    short8 r;
#pragma unroll
    for (int i = 0; i < 4; ++i) {
        r[i]     = (short)f2bf(a[i]);
        r[i + 4] = (short)f2bf(c[i]);
    }
    return r;
}

__device__ __forceinline__ void async_copy16(const float* g, float* lds) {
    __builtin_amdgcn_global_load_lds(
        (const __attribute__((address_space(1))) void*)g,
        (__attribute__((address_space(3))) void*)lds, 16, 0, 0);
}

__global__ __launch_bounds__(256) void egat_mfma_kernel(
    const float* __restrict__ hn,   // [N_NODES,128]
    const float* __restrict__ he,   // [E,128]
    const int*   __restrict__ src,
    const int*   __restrict__ dst,
    const float* __restrict__ W,    // [16,384]
    const float* __restrict__ b,    // [16]
    float*       __restrict__ out,  // [E,16]
    int n_tiles, int tiles_per_wave)
{
    __shared__ __align__(16) unsigned short w_lds[16 * W_ROW_S];   // 12544B
    __shared__ __align__(16) float he_lds[4 * HE_WAVE_F];          // 36864B

    const int tid  = threadIdx.x;
    const int wib  = tid >> 6;            // wave in block
    const int lane = tid & 63;
    const int l    = lane & 15;           // edge-in-tile (A) / out-col & W-row (B)
    const int quad = lane >> 4;
    const int off  = quad * 8;            // k sub-offset (floats) in a 32-wide step

    // --- W -> LDS as bf16, padded rows (one-time) ---
    for (int i = tid; i < 16 * KTOT; i += 256) {
        int row = i / KTOT, col = i - row * KTOT;
        w_lds[row * W_ROW_S + col] = f2bf(W[i]);
    }
    __syncthreads();

    // --- per-lane staging offsets: LDS chunk (j,lane) -> he-tile float offset ---
    // LDS byte x = j*1024 + lane*16 maps to (row r = x/528, col c = x%528);
    // c<512 -> data at tile byte r*512+c; else pad (dummy addr, never read).
    int goff[9];
#pragma unroll
    for (int j = 0; j < 9; ++j) {
        int x = j * 1024 + lane * 16;
        int r = x / HE_ROW_B;
        int c = x - r * HE_ROW_B;
        goff[j] = (r < 16 && c < 512) ? (r * 512 + c) >> 2 : 0;
    }

    const float bias = b[l];
    float* hb = &he_lds[wib * HE_WAVE_F];

    const int wave  = (blockIdx.x * 4) + wib;
    const int tile0 = wave * tiles_per_wave;

    // prefetch indices for first tile
    int e0 = tile0 * 16 + l;
    int su = src[e0];
    int dv = dst[e0];

    for (int i = 0; i < tiles_per_wave; ++i) {
        const int tile = tile0 + i;
        if (tile >= n_tiles) break;

        // (1) kick off he staging for this tile (9 x 1KB coalesced DMA)
        const float* hp = he + (size_t)tile * (16 * D);
#pragma unroll
        for (int j = 0; j < 9; ++j)
            async_copy16(hp + goff[j], hb + j * 256);

        // (2) prefetch next tile's indices
        int tn = tile + 1; if (tn >= n_tiles) tn = n_tiles - 1;
        const int en = tn * 16 + l;
        const int su_n = src[en];
        const int dv_n = dst[en];

        // (3) hn gather loads (16 x float4, all independent, issue early)
        const float* ru = hn + (size_t)su * D;
        const float* rv = hn + (size_t)dv * D;
        float4v au[8], av[8];
#pragma unroll
        for (int s = 0; s < 4; ++s) {
            au[2 * s]     = *(const float4v*)(ru + s * 32 + off);
            au[2 * s + 1] = *(const float4v*)(ru + s * 32 + off + 4);
            av[2 * s]     = *(const float4v*)(rv + s * 32 + off);
            av[2 * s + 1] = *(const float4v*)(rv + s * 32 + off + 4);
        }

        float4v acc = {0.f, 0.f, 0.f, 0.f};
        // K steps 0-3: hn[src]
#pragma unroll
        for (int s = 0; s < 4; ++s) {
            short8 wf = *(const short8*)&w_lds[l * W_ROW_S + s * 32 + off];
            acc = __builtin_amdgcn_mfma_f32_16x16x32_bf16(
                      cvt8(au[2 * s], au[2 * s + 1]), wf, acc, 0, 0, 0);
        }
        // K steps 4-7: hn[dst]
#pragma unroll
        for (int s = 0; s < 4; ++s) {
            short8 wf = *(const short8*)&w_lds[l * W_ROW_S + (4 + s) * 32 + off];
            acc = __builtin_amdgcn_mfma_f32_16x16x32_bf16(
                      cvt8(av[2 * s], av[2 * s + 1]), wf, acc, 0, 0, 0);
        }

        // (4) staging (and all outstanding vmem) complete
        __builtin_amdgcn_s_waitcnt(0x0F70);   // vmcnt(0), lgkm/exp unlimited

        // K steps 8-11: he from LDS (conflict-free b128 pairs)
#pragma unroll
        for (int s = 0; s < 4; ++s) {
            const int fi = l * HE_ROW_F + s * 32 + off;
            float4v ha = *(const float4v*)&hb[fi];
            float4v hc = *(const float4v*)&hb[fi + 4];
            short8 wf = *(const short8*)&w_lds[l * W_ROW_S + (8 + s) * 32 + off];
            acc = __builtin_amdgcn_mfma_f32_16x16x32_bf16(cvt8(ha, hc), wf, acc, 0, 0, 0);
        }

        // (5) epilogue: D[row=quad*4+r][col=l], 64B-coalesced dword stores
        const size_t ebase = (size_t)tile * 16;
#pragma unroll
        for (int r = 0; r < 4; ++r)
            out[(ebase + quad * 4 + r) * OUT + l] = acc[r] + bias;

        su = su_n; dv = dv_n;
    }
}

extern "C" void kernel_launch(void* const* d_in, const int* in_sizes, int n_in,
                              void* d_out, int out_size, void* d_ws, size_t ws_size,
                              hipStream_t stream) {
    const float* hn  = (const float*)d_in[0];
    const float* he  = (const float*)d_in[1];
    const int*   src = (const int*)d_in[2];
    const int*   dst = (const int*)d_in[3];
    const float* W   = (const float*)d_in[4];
    const float* b   = (const float*)d_in[5];
    float* out = (float*)d_out;

    const int E = in_sizes[2];                  // 600000
    const int n_tiles = (E + 15) / 16;          // 37500
    const int tiles_per_wave = 3;
    const int waves = (n_tiles + tiles_per_wave - 1) / tiles_per_wave;  // 12500
    const int blocks = (waves + 3) / 4;         // 3125

    egat_mfma_kernel<<<blocks, 256, 0, stream>>>(hn, he, src, dst, W, b, out,
                                                 n_tiles, tiles_per_wave);
}

// Round 3
// 446.285 us; speedup vs baseline: 1.1007x; 1.0663x over previous
//
#include <hip/hip_runtime.h>
#include <hip/hip_bf16.h>

// EGAT MLP predictor: score[e,:] = concat(hn[src[e]], hn[dst[e]], he[e]) @ W^T + b
// E=600000, N=50000, D=128, OUT=16, fp32 in/out.
//
// R2 structure: algebraic decomposition to kill the 614 MB hn-gather.
//   Phase 1 (node_proj): Pu = hn @ Wu^T + b, Pv = hn @ Wv^T   [N,16] fp32 in d_ws
//   Phase 2 (edge_score): out[e] = he[e] @ We^T + Pu[src[e]] + Pv[dst[e]]
// Gather is now 64 B/edge-side (was 512 B). Phase 2 is a pure HBM stream of he
// (307 MB) + out (38 MB): ~65 us roofline. bf16 MFMA 16x16x32, 1 wave per
// 16-row tile; A lane layout A[m=lane&15][k=quad*8+j]; C/D col=lane&15,
// row=quad*4+reg (both verified by passing benches R1/R2).

#define D   128
#define OUT 16
#define K3  384   // 3*D

typedef __attribute__((ext_vector_type(8))) short  short8;   // 8 bf16
typedef __attribute__((ext_vector_type(4))) float  float4v;

__device__ __forceinline__ unsigned short f2bf(float x) {
    unsigned u = __builtin_bit_cast(unsigned, x);
    unsigned r = u + 0x7fffu + ((u >> 16) & 1u);
    return (unsigned short)(r >> 16);
}

__device__ __forceinline__ short8 cvt8(float4v a, float4v c) {
    short8 r;
#pragma unroll
    for (int i = 0; i < 4; ++i) {
        r[i]     = (short)f2bf(a[i]);
        r[i + 4] = (short)f2bf(c[i]);
    }
    return r;
}

__device__ __forceinline__ short8 load_cvt8(const float* __restrict__ p) {
    float4v a = *(const float4v*)(p);
    float4v c = *(const float4v*)(p + 4);
    return cvt8(a, c);
}

// ---------------- Phase 1: node projections ----------------
// One wave per 16-node tile. Shared A-frags feed both Wu and Wv accumulators.
__global__ __launch_bounds__(256) void node_proj_kernel(
    const float* __restrict__ hn,   // [N,128]
    const float* __restrict__ W,    // [16,384]
    const float* __restrict__ b,    // [16]
    float*       __restrict__ Pu,   // [N,16]
    float*       __restrict__ Pv,   // [N,16]
    int n_tiles)
{
    const int wave = (blockIdx.x * blockDim.x + threadIdx.x) >> 6;
    if (wave >= n_tiles) return;
    const int lane = threadIdx.x & 63;
    const int l    = lane & 15;
    const int quad = lane >> 4;
    const int off  = quad * 8;

    short8 wu[4], wv[4];
    const float* wrow = W + l * K3;
#pragma unroll
    for (int s = 0; s < 4; ++s) {
        wu[s] = load_cvt8(wrow + s * 32 + off);
        wv[s] = load_cvt8(wrow + D + s * 32 + off);
    }
    const float bias = b[l];

    const int nbase = wave * 16;
    const float* rn = hn + (size_t)(nbase + l) * D;
    float4v accu = {0.f, 0.f, 0.f, 0.f};
    float4v accv = {0.f, 0.f, 0.f, 0.f};
#pragma unroll
    for (int s = 0; s < 4; ++s) {
        short8 af = load_cvt8(rn + s * 32 + off);
        accu = __builtin_amdgcn_mfma_f32_16x16x32_bf16(af, wu[s], accu, 0, 0, 0);
        accv = __builtin_amdgcn_mfma_f32_16x16x32_bf16(af, wv[s], accv, 0, 0, 0);
    }
#pragma unroll
    for (int r = 0; r < 4; ++r) {
        const int n = nbase + quad * 4 + r;
        Pu[n * OUT + l] = accu[r] + bias;   // bias folded here (once)
        Pv[n * OUT + l] = accv[r];
    }
}

// ---------------- Phase 2: edge scores ----------------
// One wave per 4 consecutive 16-edge tiles (We frags amortized).
__global__ __launch_bounds__(256) void edge_score_kernel(
    const float* __restrict__ he,   // [E,128]
    const int*   __restrict__ src,
    const int*   __restrict__ dst,
    const float* __restrict__ W,    // [16,384]
    const float* __restrict__ Pu,   // [N,16]
    const float* __restrict__ Pv,   // [N,16]
    float*       __restrict__ out,  // [E,16]
    int n_tiles, int tiles_per_wave)
{
    const int wave = (blockIdx.x * blockDim.x + threadIdx.x) >> 6;
    const int lane = threadIdx.x & 63;
    const int l    = lane & 15;   // A: edge-in-tile | B: W row | D: out col
    const int quad = lane >> 4;
    const int off  = quad * 8;

    // We fragments: bf16(W[l][256 + s*32 + off .. +8]), 16 VGPRs, L1-hot.
    short8 wf[4];
    const float* wrow = W + l * K3 + 2 * D;
#pragma unroll
    for (int s = 0; s < 4; ++s)
        wf[s] = load_cvt8(wrow + s * 32 + off);

    const int tile0 = wave * tiles_per_wave;
    for (int i = 0; i < tiles_per_wave; ++i) {
        const int tile = tile0 + i;
        if (tile >= n_tiles) break;
        const int ebase = tile * 16;

        // (1) index loads first — head of the longest dependency chain.
        int su[4], dv[4];
#pragma unroll
        for (int r = 0; r < 4; ++r) {
            su[r] = src[ebase + quad * 4 + r];   // broadcast across 16 lanes
            dv[r] = dst[ebase + quad * 4 + r];
        }

        // (2) he stream loads (independent of idx chain).
        const float* re = he + (size_t)(ebase + l) * D;
        float4v ha[4], hc[4];
#pragma unroll
        for (int s = 0; s < 4; ++s) {
            ha[s] = *(const float4v*)(re + s * 32 + off);
            hc[s] = *(const float4v*)(re + s * 32 + off + 4);
        }

        // (3) gather projected rows: 64 B per edge-side, 4 lines per instr.
        float pu[4], pv[4];
#pragma unroll
        for (int r = 0; r < 4; ++r) {
            pu[r] = Pu[(size_t)su[r] * OUT + l];
            pv[r] = Pv[(size_t)dv[r] * OUT + l];
        }

        // (4) he @ We^T
        float4v acc = {0.f, 0.f, 0.f, 0.f};
#pragma unroll
        for (int s = 0; s < 4; ++s)
            acc = __builtin_amdgcn_mfma_f32_16x16x32_bf16(
                      cvt8(ha[s], hc[s]), wf[s], acc, 0, 0, 0);

        // (5) epilogue: D[row=quad*4+r][col=l] + gathered projections.
#pragma unroll
        for (int r = 0; r < 4; ++r)
            out[(size_t)(ebase + quad * 4 + r) * OUT + l] = acc[r] + pu[r] + pv[r];
    }
}

extern "C" void kernel_launch(void* const* d_in, const int* in_sizes, int n_in,
                              void* d_out, int out_size, void* d_ws, size_t ws_size,
                              hipStream_t stream) {
    const float* hn  = (const float*)d_in[0];
    const float* he  = (const float*)d_in[1];
    const int*   src = (const int*)d_in[2];
    const int*   dst = (const int*)d_in[3];
    const float* W   = (const float*)d_in[4];
    const float* b   = (const float*)d_in[5];
    float* out = (float*)d_out;

    const int N = in_sizes[0] / D;      // 50000
    const int E = in_sizes[2];          // 600000

    float* Pu = (float*)d_ws;                       // N*16 fp32 = 3.2 MB
    float* Pv = (float*)d_ws + (size_t)N * OUT;     // next 3.2 MB

    // Phase 1: 3125 node tiles, 1/wave.
    const int nt_node = (N + 15) / 16;
    const int blk1 = (nt_node + 3) / 4;
    node_proj_kernel<<<blk1, 256, 0, stream>>>(hn, W, b, Pu, Pv, nt_node);

    // Phase 2: 37500 edge tiles, 4 consecutive/wave.
    const int nt_edge = (E + 15) / 16;
    const int tpw = 4;
    const int waves = (nt_edge + tpw - 1) / tpw;    // 9375
    const int blk2 = (waves + 3) / 4;               // 2344
    edge_score_kernel<<<blk2, 256, 0, stream>>>(he, src, dst, W, Pu, Pv, out,
                                                nt_edge, tpw);
}